// Round 4
// baseline (184.649 us; speedup 1.0000x reference)
//
#include <hip/hip_runtime.h>
#include <hip/hip_bf16.h>
#include <math.h>

#define DI __device__ __forceinline__

typedef short bf16x8 __attribute__((ext_vector_type(8)));
typedef float f32x4 __attribute__((ext_vector_type(4)));

constexpr int BB = 32, CC = 128, NN = 2048;
constexpr float EPSf = 1e-5f;
constexpr float RCN = 1.0f / (CC * (float)NN);

#define MFMA(a,b,c) __builtin_amdgcn_mfma_f32_16x16x32_bf16(a,b,c,0,0,0)

DI unsigned short f2b(float f){
    union { __hip_bfloat16 h; unsigned short u; } v;
    v.h = __float2bfloat16(f);
    return v.u;
}
DI float b2f(unsigned short h){
    union { unsigned u; float f; } v; v.u = ((unsigned)h) << 16;
    return v.f;
}
DI float sigm(float x){ return 1.0f / (1.0f + __expf(-x)); }

// ---------------------------------------------------------------------------
// K0: weight prep (96 blocks) + Wg1/Wg2 rowsums (1 block) + keysm (64 blocks)
// ---------------------------------------------------------------------------
__global__ __launch_bounds__(256) void k_prep(
    const float* __restrict__ Wq, const float* __restrict__ Wv,
    const float* __restrict__ Wc, const float* __restrict__ Wg1,
    const float* __restrict__ Wg2, const float* __restrict__ Wg3,
    const float* __restrict__ mem,
    unsigned short* __restrict__ Wb, float* __restrict__ rs,
    unsigned short* __restrict__ ksT)
{
    const int tid = threadIdx.x;
    if (blockIdx.x < 96) {
        const int i = blockIdx.x * 256 + tid;
        const int m = i >> 12, q = i & 4095;
        const float* src = (m==0)?Wq:(m==1)?Wv:(m==2)?Wc:(m==3)?Wg1:(m==4)?Wg2:Wg3;
        f32x4 w = *(const f32x4*)&src[q * 4];
        ushort4 p; p.x=f2b(w[0]); p.y=f2b(w[1]); p.z=f2b(w[2]); p.w=f2b(w[3]);
        *(ushort4*)&Wb[(size_t)m * 16384 + q * 4] = p;
    } else if (blockIdx.x == 96) {
        const float* src = (tid < 128) ? Wg1 : Wg2;
        const int o = tid & 127;
        float s = 0.f;
#pragma unroll
        for (int j = 0; j < 32; j++) {
            f32x4 a = *(const f32x4*)&src[o * 128 + j * 4];
            s += a[0] + a[1] + a[2] + a[3];
        }
        rs[tid] = s;
    } else {
        const int row = (blockIdx.x - 97) * 256 + tid;   // h*NN + n
        const int h = row >> 11, n = row & 2047;
        const float* p = mem + (size_t)row * 16;
        float v[16];
        f32x4 t0 = *(const f32x4*)(p);
        f32x4 t1 = *(const f32x4*)(p + 4);
        f32x4 t2 = *(const f32x4*)(p + 8);
        f32x4 t3 = *(const f32x4*)(p + 12);
#pragma unroll
        for (int j = 0; j < 4; j++) { v[j]=t0[j]; v[4+j]=t1[j]; v[8+j]=t2[j]; v[12+j]=t3[j]; }
        float mx = v[0];
#pragma unroll
        for (int x = 1; x < 16; x++) mx = fmaxf(mx, v[x]);
        float s = 0.f;
#pragma unroll
        for (int x = 0; x < 16; x++) { v[x] = __expf((v[x] - mx) * 0.25f); s += v[x]; }
        const float is = 1.0f / s;
#pragma unroll
        for (int x = 0; x < 16; x++)
            ksT[((size_t)(h * 16 + x)) * NN + n] = f2b(v[x] * is);
    }
}

// ---------------------------------------------------------------------------
// K2: fused Q,V GEMM. qT/vT[b][n][c] bf16 = relu(W X + b)
// Outputs staged through LDS -> fully coalesced 16B/lane stores.
// ---------------------------------------------------------------------------
__global__ __launch_bounds__(256,2) void k_qv(
    const float* __restrict__ in, const unsigned short* __restrict__ WqB,
    const unsigned short* __restrict__ WvB, const float* __restrict__ bq,
    const float* __restrict__ bv, unsigned short* __restrict__ qT,
    unsigned short* __restrict__ vT)
{
    __shared__ unsigned short tile[128 * 136];
    const int b = blockIdx.x >> 4, n0 = (blockIdx.x & 15) * 128;
    const int tid = threadIdx.x, l = tid & 63, wid = tid >> 6;
    const int wo = wid & 1, wn = wid >> 1, lr = l & 15, lg = l >> 4;
    f32x4 accq[4][4], accv[4][4];
    const f32x4 z = {0.f,0.f,0.f,0.f};
#pragma unroll
    for (int i = 0; i < 4; i++)
#pragma unroll
        for (int j = 0; j < 4; j++) { accq[i][j] = z; accv[i][j] = z; }
    const float* inb = in + (size_t)b * CC * NN;
#pragma unroll
    for (int ks = 0; ks < 4; ks++) {
        const int cb = ks * 32 + lg * 8;
        bf16x8 aq[4], av[4];
#pragma unroll
        for (int mf = 0; mf < 4; mf++) {
            const int o = wo*64 + mf*16 + lr;
            aq[mf] = *(const bf16x8*)&WqB[o * 128 + cb];
            av[mf] = *(const bf16x8*)&WvB[o * 128 + cb];
        }
        bf16x8 bx[4];
#pragma unroll
        for (int nf = 0; nf < 4; nf++) {
            const int n = n0 + wn*64 + nf*16 + lr;
            union { bf16x8 v; unsigned short u[8]; } t;
#pragma unroll
            for (int j = 0; j < 8; j++) t.u[j] = f2b(inb[(size_t)(cb + j) * NN + n]);
            bx[nf] = t.v;
        }
#pragma unroll
        for (int mf = 0; mf < 4; mf++)
#pragma unroll
            for (int nf = 0; nf < 4; nf++) {
                accq[mf][nf] = MFMA(aq[mf], bx[nf], accq[mf][nf]);
                accv[mf][nf] = MFMA(av[mf], bx[nf], accv[mf][nf]);
            }
    }
    // ---- q tile via LDS ----
#pragma unroll
    for (int mf = 0; mf < 4; mf++) {
        const int ob = wo*64 + mf*16 + lg*4;
        const f32x4 b4 = *(const f32x4*)&bq[ob];
#pragma unroll
        for (int nf = 0; nf < 4; nf++) {
            const int nl = wn*64 + nf*16 + lr;
            f32x4 a = accq[mf][nf];
            ushort4 pk;
            pk.x = f2b(fmaxf(a[0]+b4[0],0.f)); pk.y = f2b(fmaxf(a[1]+b4[1],0.f));
            pk.z = f2b(fmaxf(a[2]+b4[2],0.f)); pk.w = f2b(fmaxf(a[3]+b4[3],0.f));
            *(ushort4*)&tile[nl * 136 + ob] = pk;
        }
    }
    __syncthreads();
#pragma unroll
    for (int p = 0; p < 8; p++) {
        const int row = p*16 + (tid >> 4), col = (tid & 15) * 8;
        *(uint4*)&qT[((size_t)b * NN + n0 + row) * CC + col] =
            *(const uint4*)&tile[row * 136 + col];
    }
    __syncthreads();
    // ---- v tile via LDS ----
#pragma unroll
    for (int mf = 0; mf < 4; mf++) {
        const int ob = wo*64 + mf*16 + lg*4;
        const f32x4 b4 = *(const f32x4*)&bv[ob];
#pragma unroll
        for (int nf = 0; nf < 4; nf++) {
            const int nl = wn*64 + nf*16 + lr;
            f32x4 a = accv[mf][nf];
            ushort4 pk;
            pk.x = f2b(fmaxf(a[0]+b4[0],0.f)); pk.y = f2b(fmaxf(a[1]+b4[1],0.f));
            pk.z = f2b(fmaxf(a[2]+b4[2],0.f)); pk.w = f2b(fmaxf(a[3]+b4[3],0.f));
            *(ushort4*)&tile[nl * 136 + ob] = pk;
        }
    }
    __syncthreads();
#pragma unroll
    for (int p = 0; p < 8; p++) {
        const int row = p*16 + (tid >> 4), col = (tid & 15) * 8;
        *(uint4*)&vT[((size_t)b * NN + n0 + row) * CC + col] =
            *(const uint4*)&tile[row * 136 + col];
    }
}

// ---------------------------------------------------------------------------
// K3: kv[b,h] = sum_n ksT[h,:,n] x vT[b,n,h16+:]  (LDS reduce, no atomics)
// ---------------------------------------------------------------------------
__global__ __launch_bounds__(256) void k_kv(const unsigned short* __restrict__ ksT,
                                            const unsigned short* __restrict__ vT,
                                            float* __restrict__ kvb)
{
    __shared__ unsigned short vt[4 * 16 * 520];
    __shared__ float red[1024];
    const int b = blockIdx.x >> 3, h = blockIdx.x & 7;
    const int tid = threadIdx.x, l = tid & 63, wid = tid >> 6;
    const int n0 = wid * 512;
    unsigned short* vtw = vt + wid * (16 * 520);
    const unsigned short* vb = vT + ((size_t)b * NN + n0) * CC + h * 16;
#pragma unroll
    for (int r = 0; r < 8; r++) {
        const int nl = r * 64 + l;
        uint4 q0 = *(const uint4*)&vb[(size_t)nl * CC];
        uint4 q1 = *(const uint4*)&vb[(size_t)nl * CC + 8];
        const unsigned uu[8] = {q0.x,q0.y,q0.z,q0.w,q1.x,q1.y,q1.z,q1.w};
#pragma unroll
        for (int k = 0; k < 8; k++) {
            vtw[(2*k)*520 + nl]   = (unsigned short)(uu[k] & 0xffffu);
            vtw[(2*k+1)*520 + nl] = (unsigned short)(uu[k] >> 16);
        }
    }
    const int lr = l & 15, lg = l >> 4;
    const unsigned short* ka = ksT + (size_t)h * 16 * NN;
    f32x4 acc = {0.f,0.f,0.f,0.f};
#pragma unroll
    for (int kk = 0; kk < 16; kk++) {
        bf16x8 af = *(const bf16x8*)&ka[(size_t)lr * NN + n0 + kk*32 + lg*8];
        bf16x8 bf = *(const bf16x8*)&vtw[lr * 520 + kk*32 + lg*8];
        acc = MFMA(af, bf, acc);
    }
#pragma unroll
    for (int r = 0; r < 4; r++)
        red[wid * 256 + (lg*4 + r) * 16 + lr] = acc[r];
    __syncthreads();
    {
        const float s = red[tid] + red[256 + tid] + red[512 + tid] + red[768 + tid];
        kvb[((size_t)(b * 8 + h)) * 256 + tid] = s;
    }
}

// ---------------------------------------------------------------------------
// K4: fused attention + Wc GEMM + affine/residual epilogue (LDS-staged store)
// ---------------------------------------------------------------------------
__global__ __launch_bounds__(256,3) void k_attnC(
    const unsigned short* __restrict__ qT, unsigned short* __restrict__ vT,
    const float* __restrict__ kvb, const unsigned short* __restrict__ WcB,
    const float* __restrict__ bc, const float* __restrict__ saw,
    const float* __restrict__ sab, const float* __restrict__ in0f,
    float* __restrict__ part1)
{
    __shared__ float kvl[8 * 260];
    __shared__ unsigned short xc[128 * 136];
    __shared__ float red[8];
    const int b = blockIdx.x >> 4, n0 = (blockIdx.x & 15) * 128;
    const int tid = threadIdx.x;
    {
        const float* kp = kvb + (size_t)b * 2048 + (tid >> 5) * 256 + (tid & 31) * 8;
        f32x4 v0 = *(const f32x4*)kp;
        f32x4 v1 = *(const f32x4*)(kp + 4);
        float* dst = &kvl[(tid >> 5) * 260 + (tid & 31) * 8];
        *(f32x4*)dst = v0; *(f32x4*)(dst + 4) = v1;
    }
    __syncthreads();
#pragma unroll
    for (int it = 0; it < 4; it++) {
        const int idx = it * 256 + tid;
        const int nl = idx >> 3, h = idx & 7;
        const size_t base = ((size_t)b * NN + n0 + nl) * CC + h * 16;
        const unsigned short* qp = qT + base;
        const unsigned short* vp = vT + base;
        float q[16];
        {
            uint4 u0 = *(const uint4*)qp, u1 = *(const uint4*)(qp + 8);
            unsigned uu[8] = {u0.x,u0.y,u0.z,u0.w,u1.x,u1.y,u1.z,u1.w};
#pragma unroll
            for (int j = 0; j < 8; j++) {
                q[2*j]   = b2f((unsigned short)(uu[j] & 0xffffu));
                q[2*j+1] = b2f((unsigned short)(uu[j] >> 16));
            }
        }
        float mx = q[0];
#pragma unroll
        for (int x = 1; x < 16; x++) mx = fmaxf(mx, q[x]);
        float p[16]; float s = 0.f;
#pragma unroll
        for (int x = 0; x < 16; x++) { p[x] = __expf((q[x] - mx) * 0.25f); s += p[x]; }
        const float is = 1.0f / s;
        const float* kh = &kvl[h * 260];
        float r[16];
#pragma unroll
        for (int y = 0; y < 16; y++) r[y] = 0.f;
#pragma unroll
        for (int x = 0; x < 16; x++) {
            const float px = p[x];
#pragma unroll
            for (int y = 0; y < 16; y++) r[y] = fmaf(px, kh[x * 16 + y], r[y]);
        }
        uint4 w0 = *(const uint4*)vp, w1 = *(const uint4*)(vp + 8);
        unsigned vv[8] = {w0.x,w0.y,w0.z,w0.w,w1.x,w1.y,w1.z,w1.w};
        unsigned short* xp = &xc[nl * 136 + h * 16];
#pragma unroll
        for (int j2 = 0; j2 < 4; j2++) {
            ushort4 pk;
            pk.x = f2b(r[4*j2+0]*is + b2f((unsigned short)(vv[2*j2]   & 0xffffu)));
            pk.y = f2b(r[4*j2+1]*is + b2f((unsigned short)(vv[2*j2]   >> 16)));
            pk.z = f2b(r[4*j2+2]*is + b2f((unsigned short)(vv[2*j2+1] & 0xffffu)));
            pk.w = f2b(r[4*j2+3]*is + b2f((unsigned short)(vv[2*j2+1] >> 16)));
            *(ushort4*)&xp[j2 * 4] = pk;
        }
    }
    __syncthreads();
    const int l = tid & 63, wid = tid >> 6;
    const int wo = wid & 1, wn = wid >> 1, lr = l & 15, lg = l >> 4;
    f32x4 acc[4][4];
    const f32x4 z = {0.f,0.f,0.f,0.f};
#pragma unroll
    for (int i = 0; i < 4; i++)
#pragma unroll
        for (int j = 0; j < 4; j++) acc[i][j] = z;
#pragma unroll
    for (int ks = 0; ks < 4; ks++) {
        const int cb = ks * 32 + lg * 8;
        bf16x8 af[4];
#pragma unroll
        for (int mf = 0; mf < 4; mf++)
            af[mf] = *(const bf16x8*)&WcB[(wo*64 + mf*16 + lr) * 128 + cb];
        bf16x8 bx[4];
#pragma unroll
        for (int nf = 0; nf < 4; nf++)
            bx[nf] = *(const bf16x8*)&xc[(wn*64 + nf*16 + lr) * 136 + cb];
#pragma unroll
        for (int mf = 0; mf < 4; mf++)
#pragma unroll
            for (int nf = 0; nf < 4; nf++)
                acc[mf][nf] = MFMA(af[mf], bx[nf], acc[mf][nf]);
    }
    __syncthreads();   // xc reads done; reuse as output tile
    float sum = 0.f, ssq = 0.f;
#pragma unroll
    for (int mf = 0; mf < 4; mf++) {
        const int ob = wo*64 + mf*16 + lg*4;
        const f32x4 b4 = *(const f32x4*)&bc[ob];
#pragma unroll
        for (int nf = 0; nf < 4; nf++) {
            const int nl = wn*64 + nf*16 + lr;
            const int n = n0 + nl;
            f32x4 a = acc[mf][nf];
            float ys[4];
#pragma unroll
            for (int r = 0; r < 4; r++) {
                const int o = ob + r;
                const float t = fmaxf(a[r] + b4[r], 0.f);
                const float sw = saw[(size_t)o * NN + n];
                const float sb = sab[(size_t)o * NN + n];
                float y = t * sw + sb + t + in0f[((size_t)b * CC + o) * NN + n];
                sum += y; ssq += y * y;
                ys[r] = y;
            }
            ushort4 pk;
            pk.x = f2b(ys[0]); pk.y = f2b(ys[1]); pk.z = f2b(ys[2]); pk.w = f2b(ys[3]);
            *(ushort4*)&xc[nl * 136 + ob] = pk;
        }
    }
    __syncthreads();
#pragma unroll
    for (int p = 0; p < 8; p++) {
        const int row = p*16 + (tid >> 4), col = (tid & 15) * 8;
        *(uint4*)&vT[((size_t)b * NN + n0 + row) * CC + col] =
            *(const uint4*)&xc[row * 136 + col];
    }
#pragma unroll
    for (int off = 32; off > 0; off >>= 1) {
        sum += __shfl_down(sum, off);
        ssq += __shfl_down(ssq, off);
    }
    if ((tid & 63) == 0) { red[wid*2] = sum; red[wid*2+1] = ssq; }
    __syncthreads();
    if (tid == 0) {
        part1[2 * blockIdx.x]     = red[0]+red[2]+red[4]+red[6];
        part1[2 * blockIdx.x + 1] = red[1]+red[3]+red[5]+red[7];
    }
}

// ---------------------------------------------------------------------------
// K5: fused GLU(Wg1,Wg2, LN folded) + Wg3 GEMM + residual/affine epilogue
// ---------------------------------------------------------------------------
__global__ __launch_bounds__(256,2) void k_glu3(
    const unsigned short* __restrict__ y1,
    const unsigned short* __restrict__ W1B, const unsigned short* __restrict__ W2B,
    const unsigned short* __restrict__ W3B,
    const float* __restrict__ b1, const float* __restrict__ b2,
    const float* __restrict__ b3, const float* __restrict__ rs,
    const float* __restrict__ part1, const float* __restrict__ saw,
    const float* __restrict__ sab, unsigned short* __restrict__ X2,
    float* __restrict__ part2)
{
    __shared__ unsigned short yt[128 * 136];
    __shared__ unsigned short gx[128 * 136];
    __shared__ float cs[256];
    __shared__ float red[8];
    const int b = blockIdx.x >> 4, n0 = (blockIdx.x & 15) * 128;
    const int tid = threadIdx.x;
    float s0 = 0.f, q0 = 0.f;
#pragma unroll
    for (int t = 0; t < 16; t++) { s0 += part1[(b*16+t)*2]; q0 += part1[(b*16+t)*2+1]; }
    const float mean = s0 * RCN;
    const float var  = q0 * RCN - mean * mean;
    const float inv  = rsqrtf(var + EPSf);
    {
        const int cq = tid & 15;
#pragma unroll
        for (int it = 0; it < 8; it++) {
            const int n = it * 16 + (tid >> 4);
            uint4 u = *(const uint4*)&y1[((size_t)b * NN + n0 + n) * CC + cq * 8];
            *(uint4*)&yt[n * 136 + cq * 8] = u;
        }
    }
    {
        const int o = tid & 127;
        const float bb = (tid < 128) ? b1[o] : b2[o];
        cs[tid] = bb - mean * inv * rs[tid];
    }
    __syncthreads();
    const int l = tid & 63, wid = tid >> 6;
    const int wo = wid & 1, wn = wid >> 1, lr = l & 15, lg = l >> 4;
    {
        f32x4 acc1[4][4], acc2[4][4];
        const f32x4 z = {0.f,0.f,0.f,0.f};
#pragma unroll
        for (int i = 0; i < 4; i++)
#pragma unroll
            for (int j = 0; j < 4; j++) { acc1[i][j] = z; acc2[i][j] = z; }
#pragma unroll
        for (int ks = 0; ks < 4; ks++) {
            const int cb = ks * 32 + lg * 8;
            bf16x8 a1[4], a2[4];
#pragma unroll
            for (int mf = 0; mf < 4; mf++) {
                const int o = wo*64 + mf*16 + lr;
                a1[mf] = *(const bf16x8*)&W1B[o * 128 + cb];
                a2[mf] = *(const bf16x8*)&W2B[o * 128 + cb];
            }
            bf16x8 bx[4];
#pragma unroll
            for (int nf = 0; nf < 4; nf++)
                bx[nf] = *(const bf16x8*)&yt[(wn*64 + nf*16 + lr) * 136 + cb];
#pragma unroll
            for (int mf = 0; mf < 4; mf++)
#pragma unroll
                for (int nf = 0; nf < 4; nf++) {
                    acc1[mf][nf] = MFMA(a1[mf], bx[nf], acc1[mf][nf]);
                    acc2[mf][nf] = MFMA(a2[mf], bx[nf], acc2[mf][nf]);
                }
        }
#pragma unroll
        for (int mf = 0; mf < 4; mf++) {
            const int ob = wo*64 + mf*16 + lg*4;
            const f32x4 c1 = *(const f32x4*)&cs[ob];
            const f32x4 c2 = *(const f32x4*)&cs[128 + ob];
#pragma unroll
            for (int nf = 0; nf < 4; nf++) {
                const int nl = wn*64 + nf*16 + lr;
                ushort4 pk;
                float g1, g2;
                g1 = acc1[mf][nf][0]*inv + c1[0]; g2 = acc2[mf][nf][0]*inv + c2[0];
                pk.x = f2b(g1 * sigm(g2));
                g1 = acc1[mf][nf][1]*inv + c1[1]; g2 = acc2[mf][nf][1]*inv + c2[1];
                pk.y = f2b(g1 * sigm(g2));
                g1 = acc1[mf][nf][2]*inv + c1[2]; g2 = acc2[mf][nf][2]*inv + c2[2];
                pk.z = f2b(g1 * sigm(g2));
                g1 = acc1[mf][nf][3]*inv + c1[3]; g2 = acc2[mf][nf][3]*inv + c2[3];
                pk.w = f2b(g1 * sigm(g2));
                *(ushort4*)&gx[nl * 136 + ob] = pk;
            }
        }
    }
    __syncthreads();
    f32x4 acc[4][4];
    const f32x4 z = {0.f,0.f,0.f,0.f};
#pragma unroll
    for (int i = 0; i < 4; i++)
#pragma unroll
        for (int j = 0; j < 4; j++) acc[i][j] = z;
#pragma unroll
    for (int ks = 0; ks < 4; ks++) {
        const int cb = ks * 32 + lg * 8;
        bf16x8 af[4];
#pragma unroll
        for (int mf = 0; mf < 4; mf++)
            af[mf] = *(const bf16x8*)&W3B[(wo*64 + mf*16 + lr) * 128 + cb];
        bf16x8 bx[4];
#pragma unroll
        for (int nf = 0; nf < 4; nf++)
            bx[nf] = *(const bf16x8*)&gx[(wn*64 + nf*16 + lr) * 136 + cb];
#pragma unroll
        for (int mf = 0; mf < 4; mf++)
#pragma unroll
            for (int nf = 0; nf < 4; nf++)
                acc[mf][nf] = MFMA(af[mf], bx[nf], acc[mf][nf]);
    }
    __syncthreads();   // gx reads done; reuse as output tile
    float sum = 0.f, ssq = 0.f;
#pragma unroll
    for (int mf = 0; mf < 4; mf++) {
        const int ob = wo*64 + mf*16 + lg*4;
        const f32x4 b4 = *(const f32x4*)&b3[ob];
#pragma unroll
        for (int nf = 0; nf < 4; nf++) {
            const int nl = wn*64 + nf*16 + lr;
            const int n = n0 + nl;
            ushort4 yq = *(const ushort4*)&yt[nl * 136 + ob];
            f32x4 a = acc[mf][nf];
            float ys[4];
#pragma unroll
            for (int r = 0; r < 4; r++) {
                const int o = ob + r;
                const unsigned short ev = (r==0)?yq.x:(r==1)?yq.y:(r==2)?yq.z:yq.w;
                const float t = a[r] + b4[r] + (b2f(ev) - mean) * inv;
                const float sw = saw[(size_t)o * NN + n];
                const float sb = sab[(size_t)o * NN + n];
                const float y = t * sw + sb + t;
                sum += y; ssq += y * y;
                ys[r] = y;
            }
            ushort4 pk;
            pk.x = f2b(ys[0]); pk.y = f2b(ys[1]); pk.z = f2b(ys[2]); pk.w = f2b(ys[3]);
            *(ushort4*)&gx[nl * 136 + ob] = pk;
        }
    }
    __syncthreads();
#pragma unroll
    for (int p = 0; p < 8; p++) {
        const int row = p*16 + (tid >> 4), col = (tid & 15) * 8;
        *(uint4*)&X2[((size_t)b * NN + n0 + row) * CC + col] =
            *(const uint4*)&gx[row * 136 + col];
    }
#pragma unroll
    for (int off = 32; off > 0; off >>= 1) {
        sum += __shfl_down(sum, off);
        ssq += __shfl_down(ssq, off);
    }
    if ((tid & 63) == 0) { red[wid*2] = sum; red[wid*2+1] = ssq; }
    __syncthreads();
    if (tid == 0) {
        part2[2 * blockIdx.x]     = red[0]+red[2]+red[4]+red[6];
        part2[2 * blockIdx.x + 1] = red[1]+red[3]+red[5]+red[7];
    }
}

// ---------------------------------------------------------------------------
// K6: out[b][c][n] = (x2[b][n][c] - m2)/sd2  — coalesced via LDS transpose
// ---------------------------------------------------------------------------
__global__ __launch_bounds__(256) void k_lnfin(const unsigned short* __restrict__ x2,
                                               const float* __restrict__ part2,
                                               float* __restrict__ out)
{
    __shared__ unsigned ts[64 * 69];   // [cpair][n+pad]
    const int b = blockIdx.x >> 5, n0 = (blockIdx.x & 31) * 64;
    const int tid = threadIdx.x;
    float s0 = 0.f, q0 = 0.f;
#pragma unroll
    for (int t = 0; t < 16; t++) { s0 += part2[(b*16+t)*2]; q0 += part2[(b*16+t)*2+1]; }
    const float mean = s0 * RCN;
    const float var  = q0 * RCN - mean * mean;
    const float inv  = rsqrtf(var + EPSf);
    {
        const int n = tid >> 2, qd = tid & 3;
        const unsigned short* src = x2 + ((size_t)b * NN + n0 + n) * CC + qd * 32;
        uint4 a0 = *(const uint4*)(src);
        uint4 a1 = *(const uint4*)(src + 8);
        uint4 a2 = *(const uint4*)(src + 16);
        uint4 a3 = *(const uint4*)(src + 24);
        unsigned u[16] = {a0.x,a0.y,a0.z,a0.w, a1.x,a1.y,a1.z,a1.w,
                          a2.x,a2.y,a2.z,a2.w, a3.x,a3.y,a3.z,a3.w};
#pragma unroll
        for (int k = 0; k < 16; k++)
            ts[(qd * 16 + k) * 69 + n] = u[k];
    }
    __syncthreads();
#pragma unroll
    for (int pass = 0; pass < 8; pass++) {
        const int c = pass * 16 + (tid >> 4), nq = tid & 15;
        const int cp = c >> 1, hi = c & 1;
        f32x4 v;
#pragma unroll
        for (int j = 0; j < 4; j++) {
            const unsigned u = ts[cp * 69 + nq * 4 + j];
            const unsigned short hv = hi ? (unsigned short)(u >> 16)
                                         : (unsigned short)(u & 0xffffu);
            v[j] = (b2f(hv) - mean) * inv;
        }
        *(f32x4*)&out[((size_t)b * CC + c) * NN + n0 + nq * 4] = v;
    }
}

// ---------------------------------------------------------------------------
extern "C" void kernel_launch(void* const* d_in, const int* in_sizes, int n_in,
                              void* d_out, int out_size, void* d_ws, size_t ws_size,
                              hipStream_t stream)
{
    const float* input = (const float*)d_in[0];
    const float* Wq  = (const float*)d_in[1];
    const float* bq  = (const float*)d_in[2];
    const float* Wv  = (const float*)d_in[3];
    const float* bv  = (const float*)d_in[4];
    const float* Wc  = (const float*)d_in[5];
    const float* bc  = (const float*)d_in[6];
    const float* mem = (const float*)d_in[7];
    const float* saw = (const float*)d_in[8];
    const float* sab = (const float*)d_in[9];
    // nodevec1/2 (d_in[10..11]) provably unused: attn_dyn == value exactly.
    const float* Wg1 = (const float*)d_in[12];
    const float* bg1 = (const float*)d_in[13];
    const float* Wg2 = (const float*)d_in[14];
    const float* bg2 = (const float*)d_in[15];
    const float* Wg3 = (const float*)d_in[16];
    const float* bg3 = (const float*)d_in[17];
    float* out = (float*)d_out;

    unsigned char* wsb = (unsigned char*)d_ws;
    unsigned short* qT  = (unsigned short*)(wsb);                    // 16.78 MB
    unsigned short* vT  = (unsigned short*)(wsb + 16777216);         // 16.78 MB
    unsigned short* ksT = (unsigned short*)(wsb + 33554432);         // 512 KB
    float* kvb   = (float*)(wsb + 34078720);                         // 256 KB
    unsigned short* Wb  = (unsigned short*)(wsb + 34340864);         // 192 KB
    float* rs    = (float*)(wsb + 34537472);                         // 1 KB
    float* part1 = (float*)(wsb + 34538496);                         // 4 KB
    float* part2 = (float*)(wsb + 34542592);                         // 4 KB

    k_prep <<<161,  256, 0, stream>>>(Wq, Wv, Wc, Wg1, Wg2, Wg3, mem, Wb, rs, ksT);
    k_qv   <<<512,  256, 0, stream>>>(input, Wb, Wb + 16384, bq, bv, qT, vT);
    k_kv   <<<256,  256, 0, stream>>>(ksT, vT, kvb);
    k_attnC<<<512,  256, 0, stream>>>(qT, vT, kvb, Wb + 2*16384, bc, saw, sab,
                                      input, part1);
    k_glu3 <<<512,  256, 0, stream>>>(vT, Wb + 3*16384, Wb + 4*16384, Wb + 5*16384,
                                      bg1, bg2, bg3, rs, part1, saw, sab, qT, part2);
    k_lnfin<<<1024, 256, 0, stream>>>(qT, part2, out);
}

// Round 5
// 127.737 us; speedup vs baseline: 1.4455x; 1.4455x over previous
//
#include <hip/hip_runtime.h>
#include <hip/hip_bf16.h>
#include <math.h>

#define DI __device__ __forceinline__

typedef short bf16x8 __attribute__((ext_vector_type(8)));
typedef float f32x4 __attribute__((ext_vector_type(4)));

constexpr int BB = 32, CC = 128, NN = 2048;
constexpr float EPSf = 1e-5f;
constexpr float RCN = 1.0f / (CC * (float)NN);

#define MFMA(a,b,c) __builtin_amdgcn_mfma_f32_16x16x32_bf16(a,b,c,0,0,0)

DI unsigned short f2b(float f){
    union { __hip_bfloat16 h; unsigned short u; } v;
    v.h = __float2bfloat16(f);
    return v.u;
}
DI float b2f(unsigned short h){
    union { unsigned u; float f; } v; v.u = ((unsigned)h) << 16;
    return v.f;
}
DI float sigm(float x){ return 1.0f / (1.0f + __expf(-x)); }

// ---------------------------------------------------------------------------
// K0: weight prep (96 blocks) + Wg1/Wg2 rowsums (1 block) + keysm (64 blocks)
// ---------------------------------------------------------------------------
__global__ __launch_bounds__(256) void k_prep(
    const float* __restrict__ Wq, const float* __restrict__ Wv,
    const float* __restrict__ Wc, const float* __restrict__ Wg1,
    const float* __restrict__ Wg2, const float* __restrict__ Wg3,
    const float* __restrict__ mem,
    unsigned short* __restrict__ Wb, float* __restrict__ rs,
    unsigned short* __restrict__ ksT)
{
    const int tid = threadIdx.x;
    if (blockIdx.x < 96) {
        const int i = blockIdx.x * 256 + tid;
        const int m = i >> 12, q = i & 4095;
        const float* src = (m==0)?Wq:(m==1)?Wv:(m==2)?Wc:(m==3)?Wg1:(m==4)?Wg2:Wg3;
        f32x4 w = *(const f32x4*)&src[q * 4];
        ushort4 p; p.x=f2b(w[0]); p.y=f2b(w[1]); p.z=f2b(w[2]); p.w=f2b(w[3]);
        *(ushort4*)&Wb[(size_t)m * 16384 + q * 4] = p;
    } else if (blockIdx.x == 96) {
        const float* src = (tid < 128) ? Wg1 : Wg2;
        const int o = tid & 127;
        float s = 0.f;
#pragma unroll
        for (int j = 0; j < 32; j++) {
            f32x4 a = *(const f32x4*)&src[o * 128 + j * 4];
            s += a[0] + a[1] + a[2] + a[3];
        }
        rs[tid] = s;
    } else {
        const int row = (blockIdx.x - 97) * 256 + tid;   // h*NN + n
        const int h = row >> 11, n = row & 2047;
        const float* p = mem + (size_t)row * 16;
        float v[16];
        f32x4 t0 = *(const f32x4*)(p);
        f32x4 t1 = *(const f32x4*)(p + 4);
        f32x4 t2 = *(const f32x4*)(p + 8);
        f32x4 t3 = *(const f32x4*)(p + 12);
#pragma unroll
        for (int j = 0; j < 4; j++) { v[j]=t0[j]; v[4+j]=t1[j]; v[8+j]=t2[j]; v[12+j]=t3[j]; }
        float mx = v[0];
#pragma unroll
        for (int x = 1; x < 16; x++) mx = fmaxf(mx, v[x]);
        float s = 0.f;
#pragma unroll
        for (int x = 0; x < 16; x++) { v[x] = __expf((v[x] - mx) * 0.25f); s += v[x]; }
        const float is = 1.0f / s;
#pragma unroll
        for (int x = 0; x < 16; x++)
            ksT[((size_t)(h * 16 + x)) * NN + n] = f2b(v[x] * is);
    }
}

// ---------------------------------------------------------------------------
// K2: fused Q,V GEMM. qT/vT[b][n][c] bf16 = relu(W X + b)
// Outputs staged through LDS -> fully coalesced 16B/lane stores.
// ---------------------------------------------------------------------------
__global__ __launch_bounds__(256,2) void k_qv(
    const float* __restrict__ in, const unsigned short* __restrict__ WqB,
    const unsigned short* __restrict__ WvB, const float* __restrict__ bq,
    const float* __restrict__ bv, unsigned short* __restrict__ qT,
    unsigned short* __restrict__ vT)
{
    __shared__ unsigned short tile[128 * 136];
    const int b = blockIdx.x >> 4, n0 = (blockIdx.x & 15) * 128;
    const int tid = threadIdx.x, l = tid & 63, wid = tid >> 6;
    const int wo = wid & 1, wn = wid >> 1, lr = l & 15, lg = l >> 4;
    f32x4 accq[4][4], accv[4][4];
    const f32x4 z = {0.f,0.f,0.f,0.f};
#pragma unroll
    for (int i = 0; i < 4; i++)
#pragma unroll
        for (int j = 0; j < 4; j++) { accq[i][j] = z; accv[i][j] = z; }
    const float* inb = in + (size_t)b * CC * NN;
#pragma unroll
    for (int ks = 0; ks < 4; ks++) {
        const int cb = ks * 32 + lg * 8;
        bf16x8 aq[4], av[4];
#pragma unroll
        for (int mf = 0; mf < 4; mf++) {
            const int o = wo*64 + mf*16 + lr;
            aq[mf] = *(const bf16x8*)&WqB[o * 128 + cb];
            av[mf] = *(const bf16x8*)&WvB[o * 128 + cb];
        }
        bf16x8 bx[4];
#pragma unroll
        for (int nf = 0; nf < 4; nf++) {
            const int n = n0 + wn*64 + nf*16 + lr;
            union { bf16x8 v; unsigned short u[8]; } t;
#pragma unroll
            for (int j = 0; j < 8; j++) t.u[j] = f2b(inb[(size_t)(cb + j) * NN + n]);
            bx[nf] = t.v;
        }
#pragma unroll
        for (int mf = 0; mf < 4; mf++)
#pragma unroll
            for (int nf = 0; nf < 4; nf++) {
                accq[mf][nf] = MFMA(aq[mf], bx[nf], accq[mf][nf]);
                accv[mf][nf] = MFMA(av[mf], bx[nf], accv[mf][nf]);
            }
    }
    // ---- q tile via LDS ----
#pragma unroll
    for (int mf = 0; mf < 4; mf++) {
        const int ob = wo*64 + mf*16 + lg*4;
        const f32x4 b4 = *(const f32x4*)&bq[ob];
#pragma unroll
        for (int nf = 0; nf < 4; nf++) {
            const int nl = wn*64 + nf*16 + lr;
            f32x4 a = accq[mf][nf];
            ushort4 pk;
            pk.x = f2b(fmaxf(a[0]+b4[0],0.f)); pk.y = f2b(fmaxf(a[1]+b4[1],0.f));
            pk.z = f2b(fmaxf(a[2]+b4[2],0.f)); pk.w = f2b(fmaxf(a[3]+b4[3],0.f));
            *(ushort4*)&tile[nl * 136 + ob] = pk;
        }
    }
    __syncthreads();
#pragma unroll
    for (int p = 0; p < 8; p++) {
        const int row = p*16 + (tid >> 4), col = (tid & 15) * 8;
        *(uint4*)&qT[((size_t)b * NN + n0 + row) * CC + col] =
            *(const uint4*)&tile[row * 136 + col];
    }
    __syncthreads();
    // ---- v tile via LDS ----
#pragma unroll
    for (int mf = 0; mf < 4; mf++) {
        const int ob = wo*64 + mf*16 + lg*4;
        const f32x4 b4 = *(const f32x4*)&bv[ob];
#pragma unroll
        for (int nf = 0; nf < 4; nf++) {
            const int nl = wn*64 + nf*16 + lr;
            f32x4 a = accv[mf][nf];
            ushort4 pk;
            pk.x = f2b(fmaxf(a[0]+b4[0],0.f)); pk.y = f2b(fmaxf(a[1]+b4[1],0.f));
            pk.z = f2b(fmaxf(a[2]+b4[2],0.f)); pk.w = f2b(fmaxf(a[3]+b4[3],0.f));
            *(ushort4*)&tile[nl * 136 + ob] = pk;
        }
    }
    __syncthreads();
#pragma unroll
    for (int p = 0; p < 8; p++) {
        const int row = p*16 + (tid >> 4), col = (tid & 15) * 8;
        *(uint4*)&vT[((size_t)b * NN + n0 + row) * CC + col] =
            *(const uint4*)&tile[row * 136 + col];
    }
}

// ---------------------------------------------------------------------------
// K3: kv[b,h] = sum_n ksT[h,:,n] x vT[b,n,h16+:]  (LDS reduce, no atomics)
// ---------------------------------------------------------------------------
__global__ __launch_bounds__(256) void k_kv(const unsigned short* __restrict__ ksT,
                                            const unsigned short* __restrict__ vT,
                                            float* __restrict__ kvb)
{
    __shared__ unsigned short vt[4 * 16 * 520];
    __shared__ float red[1024];
    const int b = blockIdx.x >> 3, h = blockIdx.x & 7;
    const int tid = threadIdx.x, l = tid & 63, wid = tid >> 6;
    const int n0 = wid * 512;
    unsigned short* vtw = vt + wid * (16 * 520);
    const unsigned short* vb = vT + ((size_t)b * NN + n0) * CC + h * 16;
#pragma unroll
    for (int r = 0; r < 8; r++) {
        const int nl = r * 64 + l;
        uint4 q0 = *(const uint4*)&vb[(size_t)nl * CC];
        uint4 q1 = *(const uint4*)&vb[(size_t)nl * CC + 8];
        const unsigned uu[8] = {q0.x,q0.y,q0.z,q0.w,q1.x,q1.y,q1.z,q1.w};
#pragma unroll
        for (int k = 0; k < 8; k++) {
            vtw[(2*k)*520 + nl]   = (unsigned short)(uu[k] & 0xffffu);
            vtw[(2*k+1)*520 + nl] = (unsigned short)(uu[k] >> 16);
        }
    }
    const int lr = l & 15, lg = l >> 4;
    const unsigned short* ka = ksT + (size_t)h * 16 * NN;
    f32x4 acc = {0.f,0.f,0.f,0.f};
#pragma unroll
    for (int kk = 0; kk < 16; kk++) {
        bf16x8 af = *(const bf16x8*)&ka[(size_t)lr * NN + n0 + kk*32 + lg*8];
        bf16x8 bf = *(const bf16x8*)&vtw[lr * 520 + kk*32 + lg*8];
        acc = MFMA(af, bf, acc);
    }
#pragma unroll
    for (int r = 0; r < 4; r++)
        red[wid * 256 + (lg*4 + r) * 16 + lr] = acc[r];
    __syncthreads();
    {
        const float s = red[tid] + red[256 + tid] + red[512 + tid] + red[768 + tid];
        kvb[((size_t)(b * 8 + h)) * 256 + tid] = s;
    }
}

// ---------------------------------------------------------------------------
// K4: fused attention + Wc GEMM + affine/residual epilogue (LDS-staged store)
// __launch_bounds__(256,2): 128 VGPR budget — (256,3) forced 84 VGPRs and
// spilled the MFMA accumulators to scratch (R4: WRITE_SIZE 192 MB, 2x dur).
// LDS (43.5 KB) still allows 3 blocks/CU at runtime.
// ---------------------------------------------------------------------------
__global__ __launch_bounds__(256,2) void k_attnC(
    const unsigned short* __restrict__ qT, unsigned short* __restrict__ vT,
    const float* __restrict__ kvb, const unsigned short* __restrict__ WcB,
    const float* __restrict__ bc, const float* __restrict__ saw,
    const float* __restrict__ sab, const float* __restrict__ in0f,
    float* __restrict__ part1)
{
    __shared__ float kvl[8 * 260];
    __shared__ unsigned short xc[128 * 136];
    __shared__ float red[8];
    const int b = blockIdx.x >> 4, n0 = (blockIdx.x & 15) * 128;
    const int tid = threadIdx.x;
    {
        const float* kp = kvb + (size_t)b * 2048 + (tid >> 5) * 256 + (tid & 31) * 8;
        f32x4 v0 = *(const f32x4*)kp;
        f32x4 v1 = *(const f32x4*)(kp + 4);
        float* dst = &kvl[(tid >> 5) * 260 + (tid & 31) * 8];
        *(f32x4*)dst = v0; *(f32x4*)(dst + 4) = v1;
    }
    __syncthreads();
#pragma unroll
    for (int it = 0; it < 4; it++) {
        const int idx = it * 256 + tid;
        const int nl = idx >> 3, h = idx & 7;
        const size_t base = ((size_t)b * NN + n0 + nl) * CC + h * 16;
        const unsigned short* qp = qT + base;
        const unsigned short* vp = vT + base;
        float q[16];
        {
            uint4 u0 = *(const uint4*)qp, u1 = *(const uint4*)(qp + 8);
            unsigned uu[8] = {u0.x,u0.y,u0.z,u0.w,u1.x,u1.y,u1.z,u1.w};
#pragma unroll
            for (int j = 0; j < 8; j++) {
                q[2*j]   = b2f((unsigned short)(uu[j] & 0xffffu));
                q[2*j+1] = b2f((unsigned short)(uu[j] >> 16));
            }
        }
        float mx = q[0];
#pragma unroll
        for (int x = 1; x < 16; x++) mx = fmaxf(mx, q[x]);
        float p[16]; float s = 0.f;
#pragma unroll
        for (int x = 0; x < 16; x++) { p[x] = __expf((q[x] - mx) * 0.25f); s += p[x]; }
        const float is = 1.0f / s;
        const float* kh = &kvl[h * 260];
        float r[16];
#pragma unroll
        for (int y = 0; y < 16; y++) r[y] = 0.f;
#pragma unroll
        for (int x = 0; x < 16; x++) {
            const float px = p[x];
#pragma unroll
            for (int y = 0; y < 16; y++) r[y] = fmaf(px, kh[x * 16 + y], r[y]);
        }
        uint4 w0 = *(const uint4*)vp, w1 = *(const uint4*)(vp + 8);
        unsigned vv[8] = {w0.x,w0.y,w0.z,w0.w,w1.x,w1.y,w1.z,w1.w};
        unsigned short* xp = &xc[nl * 136 + h * 16];
#pragma unroll
        for (int j2 = 0; j2 < 4; j2++) {
            ushort4 pk;
            pk.x = f2b(r[4*j2+0]*is + b2f((unsigned short)(vv[2*j2]   & 0xffffu)));
            pk.y = f2b(r[4*j2+1]*is + b2f((unsigned short)(vv[2*j2]   >> 16)));
            pk.z = f2b(r[4*j2+2]*is + b2f((unsigned short)(vv[2*j2+1] & 0xffffu)));
            pk.w = f2b(r[4*j2+3]*is + b2f((unsigned short)(vv[2*j2+1] >> 16)));
            *(ushort4*)&xp[j2 * 4] = pk;
        }
    }
    __syncthreads();
    const int l = tid & 63, wid = tid >> 6;
    const int wo = wid & 1, wn = wid >> 1, lr = l & 15, lg = l >> 4;
    f32x4 acc[4][4];
    const f32x4 z = {0.f,0.f,0.f,0.f};
#pragma unroll
    for (int i = 0; i < 4; i++)
#pragma unroll
        for (int j = 0; j < 4; j++) acc[i][j] = z;
#pragma unroll
    for (int ks = 0; ks < 4; ks++) {
        const int cb = ks * 32 + lg * 8;
        bf16x8 af[4];
#pragma unroll
        for (int mf = 0; mf < 4; mf++)
            af[mf] = *(const bf16x8*)&WcB[(wo*64 + mf*16 + lr) * 128 + cb];
        bf16x8 bx[4];
#pragma unroll
        for (int nf = 0; nf < 4; nf++)
            bx[nf] = *(const bf16x8*)&xc[(wn*64 + nf*16 + lr) * 136 + cb];
#pragma unroll
        for (int mf = 0; mf < 4; mf++)
#pragma unroll
            for (int nf = 0; nf < 4; nf++)
                acc[mf][nf] = MFMA(af[mf], bx[nf], acc[mf][nf]);
    }
    __syncthreads();   // xc reads done; reuse as output tile
    float sum = 0.f, ssq = 0.f;
#pragma unroll
    for (int mf = 0; mf < 4; mf++) {
        const int ob = wo*64 + mf*16 + lg*4;
        const f32x4 b4 = *(const f32x4*)&bc[ob];
#pragma unroll
        for (int nf = 0; nf < 4; nf++) {
            const int nl = wn*64 + nf*16 + lr;
            const int n = n0 + nl;
            f32x4 a = acc[mf][nf];
            float ys[4];
#pragma unroll
            for (int r = 0; r < 4; r++) {
                const int o = ob + r;
                const float t = fmaxf(a[r] + b4[r], 0.f);
                const float sw = saw[(size_t)o * NN + n];
                const float sb = sab[(size_t)o * NN + n];
                float y = t * sw + sb + t + in0f[((size_t)b * CC + o) * NN + n];
                sum += y; ssq += y * y;
                ys[r] = y;
            }
            ushort4 pk;
            pk.x = f2b(ys[0]); pk.y = f2b(ys[1]); pk.z = f2b(ys[2]); pk.w = f2b(ys[3]);
            *(ushort4*)&xc[nl * 136 + ob] = pk;
        }
    }
    __syncthreads();
#pragma unroll
    for (int p = 0; p < 8; p++) {
        const int row = p*16 + (tid >> 4), col = (tid & 15) * 8;
        *(uint4*)&vT[((size_t)b * NN + n0 + row) * CC + col] =
            *(const uint4*)&xc[row * 136 + col];
    }
#pragma unroll
    for (int off = 32; off > 0; off >>= 1) {
        sum += __shfl_down(sum, off);
        ssq += __shfl_down(ssq, off);
    }
    if ((tid & 63) == 0) { red[wid*2] = sum; red[wid*2+1] = ssq; }
    __syncthreads();
    if (tid == 0) {
        part1[2 * blockIdx.x]     = red[0]+red[2]+red[4]+red[6];
        part1[2 * blockIdx.x + 1] = red[1]+red[3]+red[5]+red[7];
    }
}

// ---------------------------------------------------------------------------
// K5: fused GLU(Wg1,Wg2, LN folded) + Wg3 GEMM + residual/affine epilogue
// ---------------------------------------------------------------------------
__global__ __launch_bounds__(256,2) void k_glu3(
    const unsigned short* __restrict__ y1,
    const unsigned short* __restrict__ W1B, const unsigned short* __restrict__ W2B,
    const unsigned short* __restrict__ W3B,
    const float* __restrict__ b1, const float* __restrict__ b2,
    const float* __restrict__ b3, const float* __restrict__ rs,
    const float* __restrict__ part1, const float* __restrict__ saw,
    const float* __restrict__ sab, unsigned short* __restrict__ X2,
    float* __restrict__ part2)
{
    __shared__ unsigned short yt[128 * 136];
    __shared__ unsigned short gx[128 * 136];
    __shared__ float cs[256];
    __shared__ float red[8];
    const int b = blockIdx.x >> 4, n0 = (blockIdx.x & 15) * 128;
    const int tid = threadIdx.x;
    float s0 = 0.f, q0 = 0.f;
#pragma unroll
    for (int t = 0; t < 16; t++) { s0 += part1[(b*16+t)*2]; q0 += part1[(b*16+t)*2+1]; }
    const float mean = s0 * RCN;
    const float var  = q0 * RCN - mean * mean;
    const float inv  = rsqrtf(var + EPSf);
    {
        const int cq = tid & 15;
#pragma unroll
        for (int it = 0; it < 8; it++) {
            const int n = it * 16 + (tid >> 4);
            uint4 u = *(const uint4*)&y1[((size_t)b * NN + n0 + n) * CC + cq * 8];
            *(uint4*)&yt[n * 136 + cq * 8] = u;
        }
    }
    {
        const int o = tid & 127;
        const float bb = (tid < 128) ? b1[o] : b2[o];
        cs[tid] = bb - mean * inv * rs[tid];
    }
    __syncthreads();
    const int l = tid & 63, wid = tid >> 6;
    const int wo = wid & 1, wn = wid >> 1, lr = l & 15, lg = l >> 4;
    {
        f32x4 acc1[4][4], acc2[4][4];
        const f32x4 z = {0.f,0.f,0.f,0.f};
#pragma unroll
        for (int i = 0; i < 4; i++)
#pragma unroll
            for (int j = 0; j < 4; j++) { acc1[i][j] = z; acc2[i][j] = z; }
#pragma unroll
        for (int ks = 0; ks < 4; ks++) {
            const int cb = ks * 32 + lg * 8;
            bf16x8 a1[4], a2[4];
#pragma unroll
            for (int mf = 0; mf < 4; mf++) {
                const int o = wo*64 + mf*16 + lr;
                a1[mf] = *(const bf16x8*)&W1B[o * 128 + cb];
                a2[mf] = *(const bf16x8*)&W2B[o * 128 + cb];
            }
            bf16x8 bx[4];
#pragma unroll
            for (int nf = 0; nf < 4; nf++)
                bx[nf] = *(const bf16x8*)&yt[(wn*64 + nf*16 + lr) * 136 + cb];
#pragma unroll
            for (int mf = 0; mf < 4; mf++)
#pragma unroll
                for (int nf = 0; nf < 4; nf++) {
                    acc1[mf][nf] = MFMA(a1[mf], bx[nf], acc1[mf][nf]);
                    acc2[mf][nf] = MFMA(a2[mf], bx[nf], acc2[mf][nf]);
                }
        }
#pragma unroll
        for (int mf = 0; mf < 4; mf++) {
            const int ob = wo*64 + mf*16 + lg*4;
            const f32x4 c1 = *(const f32x4*)&cs[ob];
            const f32x4 c2 = *(const f32x4*)&cs[128 + ob];
#pragma unroll
            for (int nf = 0; nf < 4; nf++) {
                const int nl = wn*64 + nf*16 + lr;
                ushort4 pk;
                float g1, g2;
                g1 = acc1[mf][nf][0]*inv + c1[0]; g2 = acc2[mf][nf][0]*inv + c2[0];
                pk.x = f2b(g1 * sigm(g2));
                g1 = acc1[mf][nf][1]*inv + c1[1]; g2 = acc2[mf][nf][1]*inv + c2[1];
                pk.y = f2b(g1 * sigm(g2));
                g1 = acc1[mf][nf][2]*inv + c1[2]; g2 = acc2[mf][nf][2]*inv + c2[2];
                pk.z = f2b(g1 * sigm(g2));
                g1 = acc1[mf][nf][3]*inv + c1[3]; g2 = acc2[mf][nf][3]*inv + c2[3];
                pk.w = f2b(g1 * sigm(g2));
                *(ushort4*)&gx[nl * 136 + ob] = pk;
            }
        }
    }
    __syncthreads();
    f32x4 acc[4][4];
    const f32x4 z = {0.f,0.f,0.f,0.f};
#pragma unroll
    for (int i = 0; i < 4; i++)
#pragma unroll
        for (int j = 0; j < 4; j++) acc[i][j] = z;
#pragma unroll
    for (int ks = 0; ks < 4; ks++) {
        const int cb = ks * 32 + lg * 8;
        bf16x8 af[4];
#pragma unroll
        for (int mf = 0; mf < 4; mf++)
            af[mf] = *(const bf16x8*)&W3B[(wo*64 + mf*16 + lr) * 128 + cb];
        bf16x8 bx[4];
#pragma unroll
        for (int nf = 0; nf < 4; nf++)
            bx[nf] = *(const bf16x8*)&gx[(wn*64 + nf*16 + lr) * 136 + cb];
#pragma unroll
        for (int mf = 0; mf < 4; mf++)
#pragma unroll
            for (int nf = 0; nf < 4; nf++)
                acc[mf][nf] = MFMA(af[mf], bx[nf], acc[mf][nf]);
    }
    __syncthreads();   // gx reads done; reuse as output tile
    float sum = 0.f, ssq = 0.f;
#pragma unroll
    for (int mf = 0; mf < 4; mf++) {
        const int ob = wo*64 + mf*16 + lg*4;
        const f32x4 b4 = *(const f32x4*)&b3[ob];
#pragma unroll
        for (int nf = 0; nf < 4; nf++) {
            const int nl = wn*64 + nf*16 + lr;
            const int n = n0 + nl;
            ushort4 yq = *(const ushort4*)&yt[nl * 136 + ob];
            f32x4 a = acc[mf][nf];
            float ys[4];
#pragma unroll
            for (int r = 0; r < 4; r++) {
                const int o = ob + r;
                const unsigned short ev = (r==0)?yq.x:(r==1)?yq.y:(r==2)?yq.z:yq.w;
                const float t = a[r] + b4[r] + (b2f(ev) - mean) * inv;
                const float sw = saw[(size_t)o * NN + n];
                const float sb = sab[(size_t)o * NN + n];
                const float y = t * sw + sb + t;
                sum += y; ssq += y * y;
                ys[r] = y;
            }
            ushort4 pk;
            pk.x = f2b(ys[0]); pk.y = f2b(ys[1]); pk.z = f2b(ys[2]); pk.w = f2b(ys[3]);
            *(ushort4*)&gx[nl * 136 + ob] = pk;
        }
    }
    __syncthreads();
#pragma unroll
    for (int p = 0; p < 8; p++) {
        const int row = p*16 + (tid >> 4), col = (tid & 15) * 8;
        *(uint4*)&X2[((size_t)b * NN + n0 + row) * CC + col] =
            *(const uint4*)&gx[row * 136 + col];
    }
#pragma unroll
    for (int off = 32; off > 0; off >>= 1) {
        sum += __shfl_down(sum, off);
        ssq += __shfl_down(ssq, off);
    }
    if ((tid & 63) == 0) { red[wid*2] = sum; red[wid*2+1] = ssq; }
    __syncthreads();
    if (tid == 0) {
        part2[2 * blockIdx.x]     = red[0]+red[2]+red[4]+red[6];
        part2[2 * blockIdx.x + 1] = red[1]+red[3]+red[5]+red[7];
    }
}

// ---------------------------------------------------------------------------
// K6: out[b][c][n] = (x2[b][n][c] - m2)/sd2  — coalesced via LDS transpose
// ---------------------------------------------------------------------------
__global__ __launch_bounds__(256) void k_lnfin(const unsigned short* __restrict__ x2,
                                               const float* __restrict__ part2,
                                               float* __restrict__ out)
{
    __shared__ unsigned ts[64 * 69];   // [cpair][n+pad]
    const int b = blockIdx.x >> 5, n0 = (blockIdx.x & 31) * 64;
    const int tid = threadIdx.x;
    float s0 = 0.f, q0 = 0.f;
#pragma unroll
    for (int t = 0; t < 16; t++) { s0 += part2[(b*16+t)*2]; q0 += part2[(b*16+t)*2+1]; }
    const float mean = s0 * RCN;
    const float var  = q0 * RCN - mean * mean;
    const float inv  = rsqrtf(var + EPSf);
    {
        const int n = tid >> 2, qd = tid & 3;
        const unsigned short* src = x2 + ((size_t)b * NN + n0 + n) * CC + qd * 32;
        uint4 a0 = *(const uint4*)(src);
        uint4 a1 = *(const uint4*)(src + 8);
        uint4 a2 = *(const uint4*)(src + 16);
        uint4 a3 = *(const uint4*)(src + 24);
        unsigned u[16] = {a0.x,a0.y,a0.z,a0.w, a1.x,a1.y,a1.z,a1.w,
                          a2.x,a2.y,a2.z,a2.w, a3.x,a3.y,a3.z,a3.w};
#pragma unroll
        for (int k = 0; k < 16; k++)
            ts[(qd * 16 + k) * 69 + n] = u[k];
    }
    __syncthreads();
#pragma unroll
    for (int pass = 0; pass < 8; pass++) {
        const int c = pass * 16 + (tid >> 4), nq = tid & 15;
        const int cp = c >> 1, hi = c & 1;
        f32x4 v;
#pragma unroll
        for (int j = 0; j < 4; j++) {
            const unsigned u = ts[cp * 69 + nq * 4 + j];
            const unsigned short hv = hi ? (unsigned short)(u >> 16)
                                         : (unsigned short)(u & 0xffffu);
            v[j] = (b2f(hv) - mean) * inv;
        }
        *(f32x4*)&out[((size_t)b * CC + c) * NN + n0 + nq * 4] = v;
    }
}

// ---------------------------------------------------------------------------
extern "C" void kernel_launch(void* const* d_in, const int* in_sizes, int n_in,
                              void* d_out, int out_size, void* d_ws, size_t ws_size,
                              hipStream_t stream)
{
    const float* input = (const float*)d_in[0];
    const float* Wq  = (const float*)d_in[1];
    const float* bq  = (const float*)d_in[2];
    const float* Wv  = (const float*)d_in[3];
    const float* bv  = (const float*)d_in[4];
    const float* Wc  = (const float*)d_in[5];
    const float* bc  = (const float*)d_in[6];
    const float* mem = (const float*)d_in[7];
    const float* saw = (const float*)d_in[8];
    const float* sab = (const float*)d_in[9];
    // nodevec1/2 (d_in[10..11]) provably unused: attn_dyn == value exactly.
    const float* Wg1 = (const float*)d_in[12];
    const float* bg1 = (const float*)d_in[13];
    const float* Wg2 = (const float*)d_in[14];
    const float* bg2 = (const float*)d_in[15];
    const float* Wg3 = (const float*)d_in[16];
    const float* bg3 = (const float*)d_in[17];
    float* out = (float*)d_out;

    unsigned char* wsb = (unsigned char*)d_ws;
    unsigned short* qT  = (unsigned short*)(wsb);                    // 16.78 MB
    unsigned short* vT  = (unsigned short*)(wsb + 16777216);         // 16.78 MB
    unsigned short* ksT = (unsigned short*)(wsb + 33554432);         // 512 KB
    float* kvb   = (float*)(wsb + 34078720);                         // 256 KB
    unsigned short* Wb  = (unsigned short*)(wsb + 34340864);         // 192 KB
    float* rs    = (float*)(wsb + 34537472);                         // 1 KB
    float* part1 = (float*)(wsb + 34538496);                         // 4 KB
    float* part2 = (float*)(wsb + 34542592);                         // 4 KB

    k_prep <<<161,  256, 0, stream>>>(Wq, Wv, Wc, Wg1, Wg2, Wg3, mem, Wb, rs, ksT);
    k_qv   <<<512,  256, 0, stream>>>(input, Wb, Wb + 16384, bq, bv, qT, vT);
    k_kv   <<<256,  256, 0, stream>>>(ksT, vT, kvb);
    k_attnC<<<512,  256, 0, stream>>>(qT, vT, kvb, Wb + 2*16384, bc, saw, sab,
                                      input, part1);
    k_glu3 <<<512,  256, 0, stream>>>(vT, Wb + 3*16384, Wb + 4*16384, Wb + 5*16384,
                                      bg1, bg2, bg3, rs, part1, saw, sab, qT, part2);
    k_lnfin<<<1024, 256, 0, stream>>>(qT, part2, out);
}

// Round 6
// 115.222 us; speedup vs baseline: 1.6025x; 1.1086x over previous
//
#include <hip/hip_runtime.h>
#include <hip/hip_bf16.h>
#include <math.h>

#define DI __device__ __forceinline__

typedef short bf16x8 __attribute__((ext_vector_type(8)));
typedef float f32x4 __attribute__((ext_vector_type(4)));

constexpr int BB = 32, CC = 128, NN = 2048;
constexpr float EPSf = 1e-5f;
constexpr float RCN = 1.0f / (CC * (float)NN);

#define MFMA(a,b,c) __builtin_amdgcn_mfma_f32_16x16x32_bf16(a,b,c,0,0,0)

DI unsigned short f2b(float f){
    union { __hip_bfloat16 h; unsigned short u; } v;
    v.h = __float2bfloat16(f);
    return v.u;
}
DI float b2f(unsigned short h){
    union { unsigned u; float f; } v; v.u = ((unsigned)h) << 16;
    return v.f;
}
DI float sigm(float x){ return 1.0f / (1.0f + __expf(-x)); }

// ---------------------------------------------------------------------------
// K0: weight prep (96 blocks) + Wg1/Wg2 rowsums (1 block) + keysm (64 blocks)
// ---------------------------------------------------------------------------
__global__ __launch_bounds__(256) void k_prep(
    const float* __restrict__ Wq, const float* __restrict__ Wv,
    const float* __restrict__ Wc, const float* __restrict__ Wg1,
    const float* __restrict__ Wg2, const float* __restrict__ Wg3,
    const float* __restrict__ mem,
    unsigned short* __restrict__ Wb, float* __restrict__ rs,
    unsigned short* __restrict__ ksT)
{
    const int tid = threadIdx.x;
    if (blockIdx.x < 96) {
        const int i = blockIdx.x * 256 + tid;
        const int m = i >> 12, q = i & 4095;
        const float* src = (m==0)?Wq:(m==1)?Wv:(m==2)?Wc:(m==3)?Wg1:(m==4)?Wg2:Wg3;
        f32x4 w = *(const f32x4*)&src[q * 4];
        ushort4 p; p.x=f2b(w[0]); p.y=f2b(w[1]); p.z=f2b(w[2]); p.w=f2b(w[3]);
        *(ushort4*)&Wb[(size_t)m * 16384 + q * 4] = p;
    } else if (blockIdx.x == 96) {
        const float* src = (tid < 128) ? Wg1 : Wg2;
        const int o = tid & 127;
        float s = 0.f;
#pragma unroll
        for (int j = 0; j < 32; j++) {
            f32x4 a = *(const f32x4*)&src[o * 128 + j * 4];
            s += a[0] + a[1] + a[2] + a[3];
        }
        rs[tid] = s;
    } else {
        const int row = (blockIdx.x - 97) * 256 + tid;   // h*NN + n
        const int h = row >> 11, n = row & 2047;
        const float* p = mem + (size_t)row * 16;
        float v[16];
        f32x4 t0 = *(const f32x4*)(p);
        f32x4 t1 = *(const f32x4*)(p + 4);
        f32x4 t2 = *(const f32x4*)(p + 8);
        f32x4 t3 = *(const f32x4*)(p + 12);
#pragma unroll
        for (int j = 0; j < 4; j++) { v[j]=t0[j]; v[4+j]=t1[j]; v[8+j]=t2[j]; v[12+j]=t3[j]; }
        float mx = v[0];
#pragma unroll
        for (int x = 1; x < 16; x++) mx = fmaxf(mx, v[x]);
        float s = 0.f;
#pragma unroll
        for (int x = 0; x < 16; x++) { v[x] = __expf((v[x] - mx) * 0.25f); s += v[x]; }
        const float is = 1.0f / s;
#pragma unroll
        for (int x = 0; x < 16; x++)
            ksT[((size_t)(h * 16 + x)) * NN + n] = f2b(v[x] * is);
    }
}

// ---------------------------------------------------------------------------
// K2: fused Q,V GEMM. qT/vT[b][n][c] bf16 = relu(W X + b); also writes the
// bf16 input transpose inT[b][n][c] (fragments reused) for attnC's residual.
// All outputs staged through LDS -> fully coalesced 16B/lane stores.
// ---------------------------------------------------------------------------
__global__ __launch_bounds__(256,2) void k_qv(
    const float* __restrict__ in, const unsigned short* __restrict__ WqB,
    const unsigned short* __restrict__ WvB, const float* __restrict__ bq,
    const float* __restrict__ bv, unsigned short* __restrict__ qT,
    unsigned short* __restrict__ vT, unsigned short* __restrict__ inT)
{
    __shared__ unsigned short tile[128 * 136];
    const int b = blockIdx.x >> 4, n0 = (blockIdx.x & 15) * 128;
    const int tid = threadIdx.x, l = tid & 63, wid = tid >> 6;
    const int wo = wid & 1, wn = wid >> 1, lr = l & 15, lg = l >> 4;
    f32x4 accq[4][4], accv[4][4];
    const f32x4 z = {0.f,0.f,0.f,0.f};
#pragma unroll
    for (int i = 0; i < 4; i++)
#pragma unroll
        for (int j = 0; j < 4; j++) { accq[i][j] = z; accv[i][j] = z; }
    const float* inb = in + (size_t)b * CC * NN;
#pragma unroll
    for (int ks = 0; ks < 4; ks++) {
        const int cb = ks * 32 + lg * 8;
        bf16x8 aq[4], av[4];
#pragma unroll
        for (int mf = 0; mf < 4; mf++) {
            const int o = wo*64 + mf*16 + lr;
            aq[mf] = *(const bf16x8*)&WqB[o * 128 + cb];
            av[mf] = *(const bf16x8*)&WvB[o * 128 + cb];
        }
        bf16x8 bx[4];
#pragma unroll
        for (int nf = 0; nf < 4; nf++) {
            const int n = n0 + wn*64 + nf*16 + lr;
            union { bf16x8 v; unsigned short u[8]; } t;
#pragma unroll
            for (int j = 0; j < 8; j++) t.u[j] = f2b(inb[(size_t)(cb + j) * NN + n]);
            bx[nf] = t.v;
        }
        if (wo == 0) {   // stash bf16 input fragments -> inT tile (rows disjoint per wave)
#pragma unroll
            for (int nf = 0; nf < 4; nf++)
                *(bf16x8*)&tile[(wn*64 + nf*16 + lr) * 136 + cb] = bx[nf];
        }
#pragma unroll
        for (int mf = 0; mf < 4; mf++)
#pragma unroll
            for (int nf = 0; nf < 4; nf++) {
                accq[mf][nf] = MFMA(aq[mf], bx[nf], accq[mf][nf]);
                accv[mf][nf] = MFMA(av[mf], bx[nf], accv[mf][nf]);
            }
    }
    __syncthreads();
#pragma unroll
    for (int p = 0; p < 8; p++) {
        const int row = p*16 + (tid >> 4), col = (tid & 15) * 8;
        *(uint4*)&inT[((size_t)b * NN + n0 + row) * CC + col] =
            *(const uint4*)&tile[row * 136 + col];
    }
    __syncthreads();
    // ---- q tile via LDS ----
#pragma unroll
    for (int mf = 0; mf < 4; mf++) {
        const int ob = wo*64 + mf*16 + lg*4;
        const f32x4 b4 = *(const f32x4*)&bq[ob];
#pragma unroll
        for (int nf = 0; nf < 4; nf++) {
            const int nl = wn*64 + nf*16 + lr;
            f32x4 a = accq[mf][nf];
            ushort4 pk;
            pk.x = f2b(fmaxf(a[0]+b4[0],0.f)); pk.y = f2b(fmaxf(a[1]+b4[1],0.f));
            pk.z = f2b(fmaxf(a[2]+b4[2],0.f)); pk.w = f2b(fmaxf(a[3]+b4[3],0.f));
            *(ushort4*)&tile[nl * 136 + ob] = pk;
        }
    }
    __syncthreads();
#pragma unroll
    for (int p = 0; p < 8; p++) {
        const int row = p*16 + (tid >> 4), col = (tid & 15) * 8;
        *(uint4*)&qT[((size_t)b * NN + n0 + row) * CC + col] =
            *(const uint4*)&tile[row * 136 + col];
    }
    __syncthreads();
    // ---- v tile via LDS ----
#pragma unroll
    for (int mf = 0; mf < 4; mf++) {
        const int ob = wo*64 + mf*16 + lg*4;
        const f32x4 b4 = *(const f32x4*)&bv[ob];
#pragma unroll
        for (int nf = 0; nf < 4; nf++) {
            const int nl = wn*64 + nf*16 + lr;
            f32x4 a = accv[mf][nf];
            ushort4 pk;
            pk.x = f2b(fmaxf(a[0]+b4[0],0.f)); pk.y = f2b(fmaxf(a[1]+b4[1],0.f));
            pk.z = f2b(fmaxf(a[2]+b4[2],0.f)); pk.w = f2b(fmaxf(a[3]+b4[3],0.f));
            *(ushort4*)&tile[nl * 136 + ob] = pk;
        }
    }
    __syncthreads();
#pragma unroll
    for (int p = 0; p < 8; p++) {
        const int row = p*16 + (tid >> 4), col = (tid & 15) * 8;
        *(uint4*)&vT[((size_t)b * NN + n0 + row) * CC + col] =
            *(const uint4*)&tile[row * 136 + col];
    }
}

// ---------------------------------------------------------------------------
// K3: kv[b,h] = sum_n ksT[h,:,n] x vT[b,n,h16+:]  (LDS reduce, no atomics)
// ---------------------------------------------------------------------------
__global__ __launch_bounds__(256) void k_kv(const unsigned short* __restrict__ ksT,
                                            const unsigned short* __restrict__ vT,
                                            float* __restrict__ kvb)
{
    __shared__ unsigned short vt[4 * 16 * 520];
    __shared__ float red[1024];
    const int b = blockIdx.x >> 3, h = blockIdx.x & 7;
    const int tid = threadIdx.x, l = tid & 63, wid = tid >> 6;
    const int n0 = wid * 512;
    unsigned short* vtw = vt + wid * (16 * 520);
    const unsigned short* vb = vT + ((size_t)b * NN + n0) * CC + h * 16;
#pragma unroll
    for (int r = 0; r < 8; r++) {
        const int nl = r * 64 + l;
        uint4 q0 = *(const uint4*)&vb[(size_t)nl * CC];
        uint4 q1 = *(const uint4*)&vb[(size_t)nl * CC + 8];
        const unsigned uu[8] = {q0.x,q0.y,q0.z,q0.w,q1.x,q1.y,q1.z,q1.w};
#pragma unroll
        for (int k = 0; k < 8; k++) {
            vtw[(2*k)*520 + nl]   = (unsigned short)(uu[k] & 0xffffu);
            vtw[(2*k+1)*520 + nl] = (unsigned short)(uu[k] >> 16);
        }
    }
    const int lr = l & 15, lg = l >> 4;
    const unsigned short* ka = ksT + (size_t)h * 16 * NN;
    f32x4 acc = {0.f,0.f,0.f,0.f};
#pragma unroll
    for (int kk = 0; kk < 16; kk++) {
        bf16x8 af = *(const bf16x8*)&ka[(size_t)lr * NN + n0 + kk*32 + lg*8];
        bf16x8 bf = *(const bf16x8*)&vtw[lr * 520 + kk*32 + lg*8];
        acc = MFMA(af, bf, acc);
    }
#pragma unroll
    for (int r = 0; r < 4; r++)
        red[wid * 256 + (lg*4 + r) * 16 + lr] = acc[r];
    __syncthreads();
    {
        const float s = red[tid] + red[256 + tid] + red[512 + tid] + red[768 + tid];
        kvb[((size_t)(b * 8 + h)) * 256 + tid] = s;
    }
}

// ---------------------------------------------------------------------------
// K4: fused attention + Wc GEMM + affine/residual epilogue.
// Phase A uses STREAMING softmax (no q[16]/p[16] arrays, unroll 1): R5 showed
// the unrolled 48-reg body spilled ~180 dwords/thread -> 94 MB of scratch HBM
// writes. Keep live state ~45 VGPRs.
// ---------------------------------------------------------------------------
__global__ __launch_bounds__(256,2) void k_attnC(
    const unsigned short* __restrict__ qT, unsigned short* __restrict__ vT,
    const float* __restrict__ kvb, const unsigned short* __restrict__ WcB,
    const float* __restrict__ bc, const float* __restrict__ saw,
    const float* __restrict__ sab, const unsigned short* __restrict__ inT,
    float* __restrict__ part1)
{
    __shared__ float kvl[8 * 260];
    __shared__ unsigned short xc[128 * 136];
    __shared__ float red[8];
    const int b = blockIdx.x >> 4, n0 = (blockIdx.x & 15) * 128;
    const int tid = threadIdx.x;
    {
        const float* kp = kvb + (size_t)b * 2048 + (tid >> 5) * 256 + (tid & 31) * 8;
        f32x4 v0 = *(const f32x4*)kp;
        f32x4 v1 = *(const f32x4*)(kp + 4);
        float* dst = &kvl[(tid >> 5) * 260 + (tid & 31) * 8];
        *(f32x4*)dst = v0; *(f32x4*)(dst + 4) = v1;
    }
    __syncthreads();
#pragma unroll 1
    for (int it = 0; it < 4; it++) {
        const int idx = it * 256 + tid;
        const int nl = idx >> 3, h = idx & 7;
        const size_t base = ((size_t)b * NN + n0 + nl) * CC + h * 16;
        uint4 u0 = *(const uint4*)(qT + base);
        uint4 u1 = *(const uint4*)(qT + base + 8);
        uint4 w0 = *(const uint4*)(vT + base);
        uint4 w1 = *(const uint4*)(vT + base + 8);
        unsigned uu[8] = {u0.x,u0.y,u0.z,u0.w,u1.x,u1.y,u1.z,u1.w};
        float mx = -1e30f;
#pragma unroll
        for (int j = 0; j < 8; j++) {
            mx = fmaxf(mx, b2f((unsigned short)(uu[j] & 0xffffu)));
            mx = fmaxf(mx, b2f((unsigned short)(uu[j] >> 16)));
        }
        const float* kh = &kvl[h * 260];
        f32x4 r0 = {0,0,0,0}, r1 = {0,0,0,0}, r2 = {0,0,0,0}, r3 = {0,0,0,0};
        float s = 0.f;
#pragma unroll
        for (int x = 0; x < 16; x++) {
            const unsigned short qh = (x & 1) ? (unsigned short)(uu[x >> 1] >> 16)
                                              : (unsigned short)(uu[x >> 1] & 0xffffu);
            const float e = __expf((b2f(qh) - mx) * 0.25f);
            s += e;
            const f32x4 k0 = *(const f32x4*)&kh[x * 16];
            const f32x4 k1 = *(const f32x4*)&kh[x * 16 + 4];
            const f32x4 k2 = *(const f32x4*)&kh[x * 16 + 8];
            const f32x4 k3 = *(const f32x4*)&kh[x * 16 + 12];
#pragma unroll
            for (int j = 0; j < 4; j++) {
                r0[j] = fmaf(e, k0[j], r0[j]);
                r1[j] = fmaf(e, k1[j], r1[j]);
                r2[j] = fmaf(e, k2[j], r2[j]);
                r3[j] = fmaf(e, k3[j], r3[j]);
            }
        }
        const float is = 1.0f / s;
        unsigned vv[8] = {w0.x,w0.y,w0.z,w0.w,w1.x,w1.y,w1.z,w1.w};
        unsigned short* xp = &xc[nl * 136 + h * 16];
#pragma unroll
        for (int j2 = 0; j2 < 4; j2++) {
            const f32x4 rr = (j2==0)?r0:(j2==1)?r1:(j2==2)?r2:r3;
            ushort4 pk;
            pk.x = f2b(rr[0]*is + b2f((unsigned short)(vv[2*j2]   & 0xffffu)));
            pk.y = f2b(rr[1]*is + b2f((unsigned short)(vv[2*j2]   >> 16)));
            pk.z = f2b(rr[2]*is + b2f((unsigned short)(vv[2*j2+1] & 0xffffu)));
            pk.w = f2b(rr[3]*is + b2f((unsigned short)(vv[2*j2+1] >> 16)));
            *(ushort4*)&xp[j2 * 4] = pk;
        }
    }
    __syncthreads();
    const int l = tid & 63, wid = tid >> 6;
    const int wo = wid & 1, wn = wid >> 1, lr = l & 15, lg = l >> 4;
    f32x4 acc[4][4];
    const f32x4 z = {0.f,0.f,0.f,0.f};
#pragma unroll
    for (int i = 0; i < 4; i++)
#pragma unroll
        for (int j = 0; j < 4; j++) acc[i][j] = z;
#pragma unroll
    for (int ks = 0; ks < 4; ks++) {
        const int cb = ks * 32 + lg * 8;
        bf16x8 af[4];
#pragma unroll
        for (int mf = 0; mf < 4; mf++)
            af[mf] = *(const bf16x8*)&WcB[(wo*64 + mf*16 + lr) * 128 + cb];
        bf16x8 bx[4];
#pragma unroll
        for (int nf = 0; nf < 4; nf++)
            bx[nf] = *(const bf16x8*)&xc[(wn*64 + nf*16 + lr) * 136 + cb];
#pragma unroll
        for (int mf = 0; mf < 4; mf++)
#pragma unroll
            for (int nf = 0; nf < 4; nf++)
                acc[mf][nf] = MFMA(af[mf], bx[nf], acc[mf][nf]);
    }
    __syncthreads();   // xc reads done; reuse as output tile
    float sum = 0.f, ssq = 0.f;
#pragma unroll
    for (int mf = 0; mf < 4; mf++) {
        const int ob = wo*64 + mf*16 + lg*4;
        const f32x4 b4 = *(const f32x4*)&bc[ob];
#pragma unroll
        for (int nf = 0; nf < 4; nf++) {
            const int nl = wn*64 + nf*16 + lr;
            const int n = n0 + nl;
            f32x4 a = acc[mf][nf];
            const ushort4 iu = *(const ushort4*)&inT[((size_t)b * NN + n) * CC + ob];
            float ys[4];
#pragma unroll
            for (int r = 0; r < 4; r++) {
                const int o = ob + r;
                const float t = fmaxf(a[r] + b4[r], 0.f);
                const float sw = saw[(size_t)o * NN + n];
                const float sb = sab[(size_t)o * NN + n];
                const unsigned short iv = (r==0)?iu.x:(r==1)?iu.y:(r==2)?iu.z:iu.w;
                float y = t * sw + sb + t + b2f(iv);
                sum += y; ssq += y * y;
                ys[r] = y;
            }
            ushort4 pk;
            pk.x = f2b(ys[0]); pk.y = f2b(ys[1]); pk.z = f2b(ys[2]); pk.w = f2b(ys[3]);
            *(ushort4*)&xc[nl * 136 + ob] = pk;
        }
    }
    __syncthreads();
#pragma unroll
    for (int p = 0; p < 8; p++) {
        const int row = p*16 + (tid >> 4), col = (tid & 15) * 8;
        *(uint4*)&vT[((size_t)b * NN + n0 + row) * CC + col] =
            *(const uint4*)&xc[row * 136 + col];
    }
#pragma unroll
    for (int off = 32; off > 0; off >>= 1) {
        sum += __shfl_down(sum, off);
        ssq += __shfl_down(ssq, off);
    }
    if ((tid & 63) == 0) { red[wid*2] = sum; red[wid*2+1] = ssq; }
    __syncthreads();
    if (tid == 0) {
        part1[2 * blockIdx.x]     = red[0]+red[2]+red[4]+red[6];
        part1[2 * blockIdx.x + 1] = red[1]+red[3]+red[5]+red[7];
    }
}

// ---------------------------------------------------------------------------
// K5: fused GLU(Wg1,Wg2, LN folded) + Wg3 GEMM + residual/affine epilogue
// ---------------------------------------------------------------------------
__global__ __launch_bounds__(256,2) void k_glu3(
    const unsigned short* __restrict__ y1,
    const unsigned short* __restrict__ W1B, const unsigned short* __restrict__ W2B,
    const unsigned short* __restrict__ W3B,
    const float* __restrict__ b1, const float* __restrict__ b2,
    const float* __restrict__ b3, const float* __restrict__ rs,
    const float* __restrict__ part1, const float* __restrict__ saw,
    const float* __restrict__ sab, unsigned short* __restrict__ X2,
    float* __restrict__ part2)
{
    __shared__ unsigned short yt[128 * 136];
    __shared__ unsigned short gx[128 * 136];
    __shared__ float cs[256];
    __shared__ float red[8];
    const int b = blockIdx.x >> 4, n0 = (blockIdx.x & 15) * 128;
    const int tid = threadIdx.x;
    float s0 = 0.f, q0 = 0.f;
#pragma unroll
    for (int t = 0; t < 16; t++) { s0 += part1[(b*16+t)*2]; q0 += part1[(b*16+t)*2+1]; }
    const float mean = s0 * RCN;
    const float var  = q0 * RCN - mean * mean;
    const float inv  = rsqrtf(var + EPSf);
    {
        const int cq = tid & 15;
#pragma unroll
        for (int it = 0; it < 8; it++) {
            const int n = it * 16 + (tid >> 4);
            uint4 u = *(const uint4*)&y1[((size_t)b * NN + n0 + n) * CC + cq * 8];
            *(uint4*)&yt[n * 136 + cq * 8] = u;
        }
    }
    {
        const int o = tid & 127;
        const float bb = (tid < 128) ? b1[o] : b2[o];
        cs[tid] = bb - mean * inv * rs[tid];
    }
    __syncthreads();
    const int l = tid & 63, wid = tid >> 6;
    const int wo = wid & 1, wn = wid >> 1, lr = l & 15, lg = l >> 4;
    {
        f32x4 acc1[4][4], acc2[4][4];
        const f32x4 z = {0.f,0.f,0.f,0.f};
#pragma unroll
        for (int i = 0; i < 4; i++)
#pragma unroll
            for (int j = 0; j < 4; j++) { acc1[i][j] = z; acc2[i][j] = z; }
#pragma unroll
        for (int ks = 0; ks < 4; ks++) {
            const int cb = ks * 32 + lg * 8;
            bf16x8 a1[4], a2[4];
#pragma unroll
            for (int mf = 0; mf < 4; mf++) {
                const int o = wo*64 + mf*16 + lr;
                a1[mf] = *(const bf16x8*)&W1B[o * 128 + cb];
                a2[mf] = *(const bf16x8*)&W2B[o * 128 + cb];
            }
            bf16x8 bx[4];
#pragma unroll
            for (int nf = 0; nf < 4; nf++)
                bx[nf] = *(const bf16x8*)&yt[(wn*64 + nf*16 + lr) * 136 + cb];
#pragma unroll
            for (int mf = 0; mf < 4; mf++)
#pragma unroll
                for (int nf = 0; nf < 4; nf++) {
                    acc1[mf][nf] = MFMA(a1[mf], bx[nf], acc1[mf][nf]);
                    acc2[mf][nf] = MFMA(a2[mf], bx[nf], acc2[mf][nf]);
                }
        }
#pragma unroll
        for (int mf = 0; mf < 4; mf++) {
            const int ob = wo*64 + mf*16 + lg*4;
            const f32x4 c1 = *(const f32x4*)&cs[ob];
            const f32x4 c2 = *(const f32x4*)&cs[128 + ob];
#pragma unroll
            for (int nf = 0; nf < 4; nf++) {
                const int nl = wn*64 + nf*16 + lr;
                ushort4 pk;
                float g1, g2;
                g1 = acc1[mf][nf][0]*inv + c1[0]; g2 = acc2[mf][nf][0]*inv + c2[0];
                pk.x = f2b(g1 * sigm(g2));
                g1 = acc1[mf][nf][1]*inv + c1[1]; g2 = acc2[mf][nf][1]*inv + c2[1];
                pk.y = f2b(g1 * sigm(g2));
                g1 = acc1[mf][nf][2]*inv + c1[2]; g2 = acc2[mf][nf][2]*inv + c2[2];
                pk.z = f2b(g1 * sigm(g2));
                g1 = acc1[mf][nf][3]*inv + c1[3]; g2 = acc2[mf][nf][3]*inv + c2[3];
                pk.w = f2b(g1 * sigm(g2));
                *(ushort4*)&gx[nl * 136 + ob] = pk;
            }
        }
    }
    __syncthreads();
    f32x4 acc[4][4];
    const f32x4 z = {0.f,0.f,0.f,0.f};
#pragma unroll
    for (int i = 0; i < 4; i++)
#pragma unroll
        for (int j = 0; j < 4; j++) acc[i][j] = z;
#pragma unroll
    for (int ks = 0; ks < 4; ks++) {
        const int cb = ks * 32 + lg * 8;
        bf16x8 af[4];
#pragma unroll
        for (int mf = 0; mf < 4; mf++)
            af[mf] = *(const bf16x8*)&W3B[(wo*64 + mf*16 + lr) * 128 + cb];
        bf16x8 bx[4];
#pragma unroll
        for (int nf = 0; nf < 4; nf++)
            bx[nf] = *(const bf16x8*)&gx[(wn*64 + nf*16 + lr) * 136 + cb];
#pragma unroll
        for (int mf = 0; mf < 4; mf++)
#pragma unroll
            for (int nf = 0; nf < 4; nf++)
                acc[mf][nf] = MFMA(af[mf], bx[nf], acc[mf][nf]);
    }
    __syncthreads();   // gx reads done; reuse as output tile
    float sum = 0.f, ssq = 0.f;
#pragma unroll
    for (int mf = 0; mf < 4; mf++) {
        const int ob = wo*64 + mf*16 + lg*4;
        const f32x4 b4 = *(const f32x4*)&b3[ob];
#pragma unroll
        for (int nf = 0; nf < 4; nf++) {
            const int nl = wn*64 + nf*16 + lr;
            const int n = n0 + nl;
            ushort4 yq = *(const ushort4*)&yt[nl * 136 + ob];
            f32x4 a = acc[mf][nf];
            float ys[4];
#pragma unroll
            for (int r = 0; r < 4; r++) {
                const int o = ob + r;
                const unsigned short ev = (r==0)?yq.x:(r==1)?yq.y:(r==2)?yq.z:yq.w;
                const float t = a[r] + b4[r] + (b2f(ev) - mean) * inv;
                const float sw = saw[(size_t)o * NN + n];
                const float sb = sab[(size_t)o * NN + n];
                const float y = t * sw + sb + t;
                sum += y; ssq += y * y;
                ys[r] = y;
            }
            ushort4 pk;
            pk.x = f2b(ys[0]); pk.y = f2b(ys[1]); pk.z = f2b(ys[2]); pk.w = f2b(ys[3]);
            *(ushort4*)&gx[nl * 136 + ob] = pk;
        }
    }
    __syncthreads();
#pragma unroll
    for (int p = 0; p < 8; p++) {
        const int row = p*16 + (tid >> 4), col = (tid & 15) * 8;
        *(uint4*)&X2[((size_t)b * NN + n0 + row) * CC + col] =
            *(const uint4*)&gx[row * 136 + col];
    }
#pragma unroll
    for (int off = 32; off > 0; off >>= 1) {
        sum += __shfl_down(sum, off);
        ssq += __shfl_down(ssq, off);
    }
    if ((tid & 63) == 0) { red[wid*2] = sum; red[wid*2+1] = ssq; }
    __syncthreads();
    if (tid == 0) {
        part2[2 * blockIdx.x]     = red[0]+red[2]+red[4]+red[6];
        part2[2 * blockIdx.x + 1] = red[1]+red[3]+red[5]+red[7];
    }
}

// ---------------------------------------------------------------------------
// K6: out[b][c][n] = (x2[b][n][c] - m2)/sd2  — coalesced via LDS transpose
// ---------------------------------------------------------------------------
__global__ __launch_bounds__(256) void k_lnfin(const unsigned short* __restrict__ x2,
                                               const float* __restrict__ part2,
                                               float* __restrict__ out)
{
    __shared__ unsigned ts[64 * 69];   // [cpair][n+pad]
    const int b = blockIdx.x >> 5, n0 = (blockIdx.x & 31) * 64;
    const int tid = threadIdx.x;
    float s0 = 0.f, q0 = 0.f;
#pragma unroll
    for (int t = 0; t < 16; t++) { s0 += part2[(b*16+t)*2]; q0 += part2[(b*16+t)*2+1]; }
    const float mean = s0 * RCN;
    const float var  = q0 * RCN - mean * mean;
    const float inv  = rsqrtf(var + EPSf);
    {
        const int n = tid >> 2, qd = tid & 3;
        const unsigned short* src = x2 + ((size_t)b * NN + n0 + n) * CC + qd * 32;
        uint4 a0 = *(const uint4*)(src);
        uint4 a1 = *(const uint4*)(src + 8);
        uint4 a2 = *(const uint4*)(src + 16);
        uint4 a3 = *(const uint4*)(src + 24);
        unsigned u[16] = {a0.x,a0.y,a0.z,a0.w, a1.x,a1.y,a1.z,a1.w,
                          a2.x,a2.y,a2.z,a2.w, a3.x,a3.y,a3.z,a3.w};
#pragma unroll
        for (int k = 0; k < 16; k++)
            ts[(qd * 16 + k) * 69 + n] = u[k];
    }
    __syncthreads();
#pragma unroll
    for (int pass = 0; pass < 8; pass++) {
        const int c = pass * 16 + (tid >> 4), nq = tid & 15;
        const int cp = c >> 1, hi = c & 1;
        f32x4 v;
#pragma unroll
        for (int j = 0; j < 4; j++) {
            const unsigned u = ts[cp * 69 + nq * 4 + j];
            const unsigned short hv = hi ? (unsigned short)(u >> 16)
                                         : (unsigned short)(u & 0xffffu);
            v[j] = (b2f(hv) - mean) * inv;
        }
        *(f32x4*)&out[((size_t)b * CC + c) * NN + n0 + nq * 4] = v;
    }
}

// ---------------------------------------------------------------------------
extern "C" void kernel_launch(void* const* d_in, const int* in_sizes, int n_in,
                              void* d_out, int out_size, void* d_ws, size_t ws_size,
                              hipStream_t stream)
{
    const float* input = (const float*)d_in[0];
    const float* Wq  = (const float*)d_in[1];
    const float* bq  = (const float*)d_in[2];
    const float* Wv  = (const float*)d_in[3];
    const float* bv  = (const float*)d_in[4];
    const float* Wc  = (const float*)d_in[5];
    const float* bc  = (const float*)d_in[6];
    const float* mem = (const float*)d_in[7];
    const float* saw = (const float*)d_in[8];
    const float* sab = (const float*)d_in[9];
    // nodevec1/2 (d_in[10..11]) provably unused: attn_dyn == value exactly.
    const float* Wg1 = (const float*)d_in[12];
    const float* bg1 = (const float*)d_in[13];
    const float* Wg2 = (const float*)d_in[14];
    const float* bg2 = (const float*)d_in[15];
    const float* Wg3 = (const float*)d_in[16];
    const float* bg3 = (const float*)d_in[17];
    float* out = (float*)d_out;

    unsigned char* wsb = (unsigned char*)d_ws;
    unsigned short* qT  = (unsigned short*)(wsb);                    // 16.78 MB
    unsigned short* vT  = (unsigned short*)(wsb + 16777216);         // 16.78 MB
    unsigned short* ksT = (unsigned short*)(wsb + 33554432);         // 512 KB
    float* kvb   = (float*)(wsb + 34078720);                         // 256 KB
    unsigned short* Wb  = (unsigned short*)(wsb + 34340864);         // 192 KB
    float* rs    = (float*)(wsb + 34537472);                         // 1 KB
    float* part1 = (float*)(wsb + 34538496);                         // 4 KB
    float* part2 = (float*)(wsb + 34542592);                         // 4 KB
    // bf16 input transpose lives in d_out's storage (33.5 MB f32 >= 16.78 MB);
    // fully rewritten by k_lnfin afterwards.
    unsigned short* inT = (unsigned short*)d_out;

    k_prep <<<161,  256, 0, stream>>>(Wq, Wv, Wc, Wg1, Wg2, Wg3, mem, Wb, rs, ksT);
    k_qv   <<<512,  256, 0, stream>>>(input, Wb, Wb + 16384, bq, bv, qT, vT, inT);
    k_kv   <<<256,  256, 0, stream>>>(ksT, vT, kvb);
    k_attnC<<<512,  256, 0, stream>>>(qT, vT, kvb, Wb + 2*16384, bc, saw, sab,
                                      inT, part1);
    k_glu3 <<<512,  256, 0, stream>>>(vT, Wb + 3*16384, Wb + 4*16384, Wb + 5*16384,
                                      bg1, bg2, bg3, rs, part1, saw, sab, qT, part2);
    k_lnfin<<<1024, 256, 0, stream>>>(qT, part2, out);
}